// Round 1
// baseline (6716.198 us; speedup 1.0000x reference)
//
#include <hip/hip_runtime.h>
#include <stdint.h>

// LSTM (B=128, T=512, I=64, H=512) persistent-kernel design:
//  - 16 independent batch-groups (8 batches each) -> independent group barriers
//  - 16 blocks/group, 32 hidden units/block, W resident in VGPRs as bf16 frags
//  - per step: one 16x16x32-bf16 MFMA chain over K=576 (512 h + 64 x),
//    gate math via quad shuffles, h exchanged via global double buffer (bf16)
//  - sync: per-group monotonic atomic counter (agent scope) + acq/rel fences
//  - fp32 final h -> classifier (block 0 of each group)

#define T_STEPS 512
#define HID 512
#define IND 64
#define NGROUPS 16
#define BPG 16          // blocks per group
#define BATCH_PG 8      // batches per group
#define UPB 32          // units per block
#define NTHREADS 512    // 8 waves; wave w owns gate-cols [w*16, w*16+16)

typedef float f32x4 __attribute__((ext_vector_type(4)));
typedef short s16x8 __attribute__((ext_vector_type(8)));

__device__ inline unsigned short f2bf(float f) {
  uint32_t u = __builtin_bit_cast(uint32_t, f);
  u += 0x7fffu + ((u >> 16) & 1u);   // round-to-nearest-even (inputs finite)
  return (unsigned short)(u >> 16);
}

__device__ inline s16x8 pack8(f32x4 a, f32x4 b) {
  s16x8 r;
  r[0] = (short)f2bf(a[0]); r[1] = (short)f2bf(a[1]);
  r[2] = (short)f2bf(a[2]); r[3] = (short)f2bf(a[3]);
  r[4] = (short)f2bf(b[0]); r[5] = (short)f2bf(b[1]);
  r[6] = (short)f2bf(b[2]); r[7] = (short)f2bf(b[3]);
  return r;
}

__device__ inline float sigm(float x) { return 1.f / (1.f + __expf(-x)); }
__device__ inline float tanh_f(float x) { return 1.f - 2.f / (1.f + __expf(2.f * x)); }

__global__ void __launch_bounds__(NTHREADS, 2)
lstm_persist(const float* __restrict__ x,   const float* __restrict__ Wih,
             const float* __restrict__ Whh, const float* __restrict__ bih,
             const float* __restrict__ bhh, const float* __restrict__ Wcls,
             const float* __restrict__ bcls, float* __restrict__ out,
             unsigned short* __restrict__ hx,  // [2][NGROUPS][16][HID] bf16, memset 0
             float* __restrict__ hfin,         // [128][HID] f32
             unsigned* __restrict__ ctrs)      // [NGROUPS][64] u32, memset 0
{
  const int g    = blockIdx.x / BPG;
  const int blk  = blockIdx.x % BPG;
  const int tid  = threadIdx.x;
  const int wave = tid >> 6;
  const int lane = tid & 63;
  const int lrow = lane & 15;   // A-operand row / D col selector
  const int lk   = lane >> 4;   // K subgroup (8 elems each)

  unsigned* ctr = ctrs + (size_t)g * 64;

  // ---- load persistent W fragments (B-operand: [gate-col][k], bf16) ----
  const int col  = wave * 16 + lrow;          // local gate-col 0..127
  const int gate = col & 3;                   // interleaved i,f,g,o
  const int unit = blk * UPB + (col >> 2);    // global hidden unit 0..511
  const int grow = gate * HID + unit;         // row of W_hh / W_ih (4H x *)

  s16x8 wf[18];
#pragma unroll
  for (int kk = 0; kk < 16; ++kk) {
    const float* p = Whh + (size_t)grow * HID + kk * 32 + lk * 8;
    wf[kk] = pack8(*(const f32x4*)p, *(const f32x4*)(p + 4));
  }
#pragma unroll
  for (int kk = 0; kk < 2; ++kk) {
    const float* p = Wih + (size_t)grow * IND + kk * 32 + lk * 8;
    wf[16 + kk] = pack8(*(const f32x4*)p, *(const f32x4*)(p + 4));
  }
  const float bias = bih[grow] + bhh[grow];

  float cst[4] = {0.f, 0.f, 0.f, 0.f};
  const int qbase = lane & ~3;                 // quad base for gate shuffles

  const int xb = g * BATCH_PG + lrow;          // batch row (valid if lrow<8)
  const float* xrow = x + (size_t)xb * (T_STEPS * IND) + lk * 8;

  const bool writer = ((lane & 3) == 0) && (lk < 2);
  const int wunit = blk * UPB + wave * 4 + (lrow >> 2);
  const s16x8 zero8 = {0, 0, 0, 0, 0, 0, 0, 0};

  for (int t = 0; t < T_STEPS; ++t) {
    const int rb = t & 1;

    // x_t A-fragments: prefetch before the barrier (x is static)
    s16x8 ax0 = zero8, ax1 = zero8;
    if (lrow < 8) {
      const float* p = xrow + (size_t)t * IND;
      ax0 = pack8(*(const f32x4*)p,        *(const f32x4*)(p + 4));
      ax1 = pack8(*(const f32x4*)(p + 32), *(const f32x4*)(p + 36));
    }

    // wait for all 16 blocks of the group to have finished step t-1
    if (tid == 0) {
      const unsigned target = (unsigned)(BPG * t);
      while (__hip_atomic_load(ctr, __ATOMIC_RELAXED, __HIP_MEMORY_SCOPE_AGENT) < target)
        __builtin_amdgcn_s_sleep(1);
      __builtin_amdgcn_fence(__ATOMIC_ACQUIRE, "agent");  // inv L1/L2 before anyone loads
    }
    __syncthreads();

    // h_t A-fragments (16 K-chunks from the exchange buffer)
    const unsigned short* hbase =
        hx + ((size_t)(rb * NGROUPS + g) * 16 + lrow) * HID + lk * 8;
    s16x8 ah[16];
#pragma unroll
    for (int kk = 0; kk < 16; ++kk)
      ah[kk] = *(const s16x8*)(hbase + kk * 32);

    f32x4 acc = {0.f, 0.f, 0.f, 0.f};
#pragma unroll
    for (int kk = 0; kk < 16; ++kk)
      acc = __builtin_amdgcn_mfma_f32_16x16x32_bf16(ah[kk], wf[kk], acc, 0, 0, 0);
    acc = __builtin_amdgcn_mfma_f32_16x16x32_bf16(ax0, wf[16], acc, 0, 0, 0);
    acc = __builtin_amdgcn_mfma_f32_16x16x32_bf16(ax1, wf[17], acc, 0, 0, 0);

    // gates: D row m=(lk*4+r) is the batch, col = gate-col; gather quad (i,f,g,o)
    float hnew[4];
#pragma unroll
    for (int r = 0; r < 4; ++r) {
      const float v  = acc[r] + bias;
      const float vi = __shfl(v, qbase + 0);
      const float vf = __shfl(v, qbase + 1);
      const float vg = __shfl(v, qbase + 2);
      const float vo = __shfl(v, qbase + 3);
      const float c  = sigm(vf) * cst[r] + sigm(vi) * tanh_f(vg);
      cst[r] = c;
      hnew[r] = sigm(vo) * tanh_f(c);
    }

    unsigned short* hwp =
        hx + (size_t)((rb ^ 1) * NGROUPS + g) * 16 * HID + wunit;
    if (writer) {
#pragma unroll
      for (int r = 0; r < 4; ++r)
        hwp[(size_t)(lk * 4 + r) * HID] = f2bf(hnew[r]);
      if (t == T_STEPS - 1) {
#pragma unroll
        for (int r = 0; r < 4; ++r)
          hfin[(size_t)(g * BATCH_PG + lk * 4 + r) * HID + wunit] = hnew[r];
      }
    }

    __syncthreads();  // drains vmcnt: all waves' stores visible in L2
    if (tid == 0) {
      __builtin_amdgcn_fence(__ATOMIC_RELEASE, "agent");  // wbl2: flush to coherent pt
      __hip_atomic_fetch_add(ctr, 1u, __ATOMIC_RELAXED, __HIP_MEMORY_SCOPE_AGENT);
    }
  }

  // ---- classifier: block 0 of each group, its 8 batches ----
  if (blk == 0) {
    if (tid == 0) {
      while (__hip_atomic_load(ctr, __ATOMIC_RELAXED, __HIP_MEMORY_SCOPE_AGENT) <
             (unsigned)(BPG * T_STEPS))
        __builtin_amdgcn_s_sleep(1);
      __builtin_amdgcn_fence(__ATOMIC_ACQUIRE, "agent");
    }
    __syncthreads();

    const int b = g * BATCH_PG + wave;  // one wave per batch
    float hv[8];
#pragma unroll
    for (int j = 0; j < 8; ++j) hv[j] = hfin[(size_t)b * HID + lane + 64 * j];
    for (int cls = 0; cls < 10; ++cls) {
      float s = 0.f;
#pragma unroll
      for (int j = 0; j < 8; ++j) s += hv[j] * Wcls[(size_t)cls * HID + lane + 64 * j];
#pragma unroll
      for (int m = 32; m >= 1; m >>= 1) s += __shfl_xor(s, m);
      if (lane == 0) out[b * 10 + cls] = s + bcls[cls];
    }
  }
}

extern "C" void kernel_launch(void* const* d_in, const int* in_sizes, int n_in,
                              void* d_out, int out_size, void* d_ws, size_t ws_size,
                              hipStream_t stream) {
  const float* x    = (const float*)d_in[0];
  const float* Wih  = (const float*)d_in[1];
  const float* Whh  = (const float*)d_in[2];
  const float* bih  = (const float*)d_in[3];
  const float* bhh  = (const float*)d_in[4];
  const float* Wcls = (const float*)d_in[5];
  const float* bcls = (const float*)d_in[6];
  float* out = (float*)d_out;

  uint8_t* ws = (uint8_t*)d_ws;
  unsigned short* hx = (unsigned short*)ws;                      // 512 KiB
  float* hfin        = (float*)(ws + 512 * 1024);                // 256 KiB
  unsigned* ctrs     = (unsigned*)(ws + 512 * 1024 + 256 * 1024); // 4 KiB

  // replay-safe re-init (ws is NOT re-poisoned between replays)
  hipMemsetAsync(hx, 0, 2 * NGROUPS * 16 * HID * sizeof(unsigned short), stream);
  hipMemsetAsync(ctrs, 0, NGROUPS * 64 * sizeof(unsigned), stream);

  void* args[] = {&x, &Wih, &Whh, &bih, &bhh, &Wcls, &bcls, &out, &hx, &hfin, &ctrs};
  hipError_t e = hipLaunchCooperativeKernel(
      reinterpret_cast<const void*>(&lstm_persist), dim3(NGROUPS * BPG),
      dim3(NTHREADS), args, 0, stream);
  if (e != hipSuccess) {
    // fallback: plain launch (grid == CU count -> co-resident in practice)
    lstm_persist<<<dim3(NGROUPS * BPG), dim3(NTHREADS), 0, stream>>>(
        x, Wih, Whh, bih, bhh, Wcls, bcls, out, hx, hfin, ctrs);
  }
}

// Round 2
// 2153.721 us; speedup vs baseline: 3.1184x; 3.1184x over previous
//
#include <hip/hip_runtime.h>
#include <stdint.h>

// LSTM (B=128, T=512, I=64, H=512) persistent kernel, round 2:
//  - 16 independent batch-groups (8 batches) x 16 blocks, W resident in VGPRs
//  - cross-block h exchange via MALL-coherent (agent-scope, sc1) relaxed
//    atomics -- NO cache-wide fences (round-1 wbl2/inv was ~11 us/step)
//  - unique h rows staged through a swizzled 16KB LDS tile to kill the 8x
//    per-wave read redundancy that sc1 (L2-bypass) loads would otherwise pay
//  - per-wave arrival polling (one __syncthreads per step, not two)

#define T_STEPS 512
#define HID 512
#define IND 64
#define NGROUPS 16
#define BPG 16          // blocks per group
#define BATCH_PG 8      // batches per group
#define UPB 32          // hidden units per block
#define NTHREADS 512    // 8 waves

typedef float f32x4 __attribute__((ext_vector_type(4)));
typedef short s16x8 __attribute__((ext_vector_type(8)));
typedef unsigned long long u64_t;
typedef unsigned long long u64x2 __attribute__((ext_vector_type(2)));

#define ALOAD(p)    __hip_atomic_load((p), __ATOMIC_RELAXED, __HIP_MEMORY_SCOPE_AGENT)
#define ASTORE(p,v) __hip_atomic_store((p), (v), __ATOMIC_RELAXED, __HIP_MEMORY_SCOPE_AGENT)

__device__ inline unsigned short f2bf(float f) {
  uint32_t u = __builtin_bit_cast(uint32_t, f);
  u += 0x7fffu + ((u >> 16) & 1u);   // RNE (inputs finite)
  return (unsigned short)(u >> 16);
}

__device__ inline s16x8 pack8(f32x4 a, f32x4 b) {
  s16x8 r;
  r[0] = (short)f2bf(a[0]); r[1] = (short)f2bf(a[1]);
  r[2] = (short)f2bf(a[2]); r[3] = (short)f2bf(a[3]);
  r[4] = (short)f2bf(b[0]); r[5] = (short)f2bf(b[1]);
  r[6] = (short)f2bf(b[2]); r[7] = (short)f2bf(b[3]);
  return r;
}

__device__ inline float sigm(float x) { return 1.f / (1.f + __expf(-x)); }
__device__ inline float tanh_f(float x) { return 1.f - 2.f / (1.f + __expf(2.f * x)); }

__global__ void __launch_bounds__(NTHREADS, 2)
lstm_persist(const float* __restrict__ x,   const float* __restrict__ Wih,
             const float* __restrict__ Whh, const float* __restrict__ bih,
             const float* __restrict__ bhh, const float* __restrict__ Wcls,
             const float* __restrict__ bcls, float* __restrict__ out,
             unsigned short* __restrict__ hx,  // [2][NGROUPS][8][HID] bf16, memset 0
             float* __restrict__ hfin,         // [128][HID] f32
             unsigned* __restrict__ ctrs)      // [NGROUPS][64] u32, memset 0
{
  // swizzled h staging tile: elem(row,col) at row*512 + ((col>>3)^(row&7))*8 + (col&7)
  __shared__ unsigned short hsm[16 * HID];  // 16 KB; rows 8..15 stay zero

  const int g    = blockIdx.x / BPG;
  const int blk  = blockIdx.x % BPG;
  const int tid  = threadIdx.x;
  const int wave = tid >> 6;
  const int lane = tid & 63;
  const int lrow = lane & 15;   // A row / D col selector
  const int lk   = lane >> 4;   // K subgroup

  unsigned* ctr = ctrs + (size_t)g * 64;

  // ---- persistent weight fragments (B operand, bf16) ----
  const int col  = wave * 16 + lrow;          // local gate-col 0..127
  const int gate = col & 3;
  const int unit = blk * UPB + (col >> 2);
  const int grow = gate * HID + unit;

  s16x8 wf[18];
#pragma unroll
  for (int kk = 0; kk < 16; ++kk) {
    const float* p = Whh + (size_t)grow * HID + kk * 32 + lk * 8;
    wf[kk] = pack8(*(const f32x4*)p, *(const f32x4*)(p + 4));
  }
#pragma unroll
  for (int kk = 0; kk < 2; ++kk) {
    const float* p = Wih + (size_t)grow * IND + kk * 32 + lk * 8;
    wf[16 + kk] = pack8(*(const f32x4*)p, *(const f32x4*)(p + 4));
  }
  const float bias = bih[grow] + bhh[grow];

  // zero LDS rows 8..15 once (padding rows of the A tile)
  {
    const s16x8 z = {0, 0, 0, 0, 0, 0, 0, 0};
    *(s16x8*)((char*)hsm + (8 + wave) * 1024 + (lane << 4)) = z;
  }

  float cst[4] = {0.f, 0.f, 0.f, 0.f};
  const int qbase = lane & ~3;
  const int xb = g * BATCH_PG + lrow;
  const float* xrow = x + (size_t)xb * (T_STEPS * IND) + lk * 8;
  const s16x8 zero8 = {0, 0, 0, 0, 0, 0, 0, 0};
  const int wunit = blk * UPB + wave * 4 + (lrow >> 2);

  for (int t = 0; t < T_STEPS; ++t) {
    const int rb = t & 1;

    // x_t fragments (plain cached loads; L2 stays warm -- no invalidates now)
    s16x8 ax0 = zero8, ax1 = zero8;
    if (lrow < 8) {
      const float* p = xrow + (size_t)t * IND;
      ax0 = pack8(*(const f32x4*)p,        *(const f32x4*)(p + 4));
      ax1 = pack8(*(const f32x4*)(p + 32), *(const f32x4*)(p + 36));
    }

    // per-wave arrival wait: all 16 blocks finished step t-1
    if (t) {
      const unsigned target = (unsigned)(BPG * t);
      while (ALOAD(ctr) < target) __builtin_amdgcn_s_sleep(1);
    }
    __asm__ volatile("" ::: "memory");  // no hoisting of h loads above the poll

    // stage: wave w sc1-loads unique row w (16B/lane) -> swizzled LDS
    {
      const u64_t* hb =
          (const u64_t*)(hx + ((size_t)(rb * NGROUPS + g) * 8 + wave) * HID) + lane * 2;
      u64x2 hv;
      hv[0] = ALOAD(hb);
      hv[1] = ALOAD(hb + 1);
      *(s16x8*)((char*)hsm + wave * 1024 + ((lane ^ wave) << 4)) =
          __builtin_bit_cast(s16x8, hv);
    }
    __syncthreads();

    // A fragments from LDS (swizzled, conflict-free within 8-row stripes)
    s16x8 ah[16];
#pragma unroll
    for (int kk = 0; kk < 16; ++kk)
      ah[kk] = *(const s16x8*)((const char*)hsm + lrow * 1024 +
                               (((lk + kk * 4) ^ (lrow & 7)) << 4));

    f32x4 acc0 = {0.f, 0.f, 0.f, 0.f}, acc1 = {0.f, 0.f, 0.f, 0.f};
#pragma unroll
    for (int kk = 0; kk < 16; kk += 2) {
      acc0 = __builtin_amdgcn_mfma_f32_16x16x32_bf16(ah[kk],     wf[kk],     acc0, 0, 0, 0);
      acc1 = __builtin_amdgcn_mfma_f32_16x16x32_bf16(ah[kk + 1], wf[kk + 1], acc1, 0, 0, 0);
    }
    acc0 = __builtin_amdgcn_mfma_f32_16x16x32_bf16(ax0, wf[16], acc0, 0, 0, 0);
    acc1 = __builtin_amdgcn_mfma_f32_16x16x32_bf16(ax1, wf[17], acc1, 0, 0, 0);

    // gates (quad shuffle: cols 4q..4q+3 are i,f,g,o of one unit)
    float hnew[4];
#pragma unroll
    for (int r = 0; r < 4; ++r) {
      const float v  = acc0[r] + acc1[r] + bias;
      const float vi = __shfl(v, qbase + 0);
      const float vf = __shfl(v, qbase + 1);
      const float vg = __shfl(v, qbase + 2);
      const float vo = __shfl(v, qbase + 3);
      const float c  = sigm(vf) * cst[r] + sigm(vi) * tanh_f(vg);
      cst[r] = c;
      hnew[r] = sigm(vo) * tanh_f(c);
    }

    // pack 4 units/u64 and sc1-store to the other buffer
    u64_t* hwb = (u64_t*)hx +
        ((size_t)((rb ^ 1) * NGROUPS + g) * 8 * HID + blk * UPB + wave * 4) / 4;
#pragma unroll
    for (int r = 0; r < 4; ++r) {
      const unsigned hs  = (unsigned)f2bf(hnew[r]);
      const unsigned p01 = hs | (__shfl_down(hs, 4) << 16);   // units u,u+1
      const unsigned p23 = __shfl_down(p01, 8);               // units u+2,u+3
      if (lrow == 0 && lk < 2)
        ASTORE(hwb + (size_t)(lk * 4 + r) * (HID / 4),
               (u64_t)p01 | ((u64_t)p23 << 32));
      if (t == T_STEPS - 1 && (lane & 3) == 0 && lk < 2)
        ASTORE((unsigned*)&hfin[(size_t)(g * BATCH_PG + lk * 4 + r) * HID + wunit],
               __builtin_bit_cast(unsigned, hnew[r]));
    }

    // all sc1 stores globally visible (write-through + vmcnt drain), then signal
    __asm__ volatile("s_waitcnt vmcnt(0)" ::: "memory");
    __syncthreads();  // also protects LDS tile reuse next step
    if (tid == 0)
      __hip_atomic_fetch_add(ctr, 1u, __ATOMIC_RELAXED, __HIP_MEMORY_SCOPE_AGENT);
  }

  // ---- classifier: block 0 of each group ----
  if (blk == 0) {
    while (ALOAD(ctr) < (unsigned)(BPG * T_STEPS)) __builtin_amdgcn_s_sleep(1);
    __asm__ volatile("" ::: "memory");

    const int b = g * BATCH_PG + wave;  // one wave per batch
    float hv[8];
#pragma unroll
    for (int j = 0; j < 8; ++j)
      hv[j] = __builtin_bit_cast(float,
                ALOAD((const unsigned*)&hfin[(size_t)b * HID + lane + 64 * j]));
    for (int cls = 0; cls < 10; ++cls) {
      float s = 0.f;
#pragma unroll
      for (int j = 0; j < 8; ++j) s += hv[j] * Wcls[(size_t)cls * HID + lane + 64 * j];
#pragma unroll
      for (int m = 32; m >= 1; m >>= 1) s += __shfl_xor(s, m);
      if (lane == 0) out[b * 10 + cls] = s + bcls[cls];
    }
  }
}

extern "C" void kernel_launch(void* const* d_in, const int* in_sizes, int n_in,
                              void* d_out, int out_size, void* d_ws, size_t ws_size,
                              hipStream_t stream) {
  const float* x    = (const float*)d_in[0];
  const float* Wih  = (const float*)d_in[1];
  const float* Whh  = (const float*)d_in[2];
  const float* bih  = (const float*)d_in[3];
  const float* bhh  = (const float*)d_in[4];
  const float* Wcls = (const float*)d_in[5];
  const float* bcls = (const float*)d_in[6];
  float* out = (float*)d_out;

  uint8_t* ws = (uint8_t*)d_ws;
  unsigned short* hx = (unsigned short*)ws;                       // 256 KiB
  float* hfin        = (float*)(ws + 256 * 1024);                 // 256 KiB
  unsigned* ctrs     = (unsigned*)(ws + 512 * 1024);              // 4 KiB

  // replay-safe re-init
  hipMemsetAsync(hx, 0, 2 * NGROUPS * 8 * HID * sizeof(unsigned short), stream);
  hipMemsetAsync(ctrs, 0, NGROUPS * 64 * sizeof(unsigned), stream);

  void* args[] = {&x, &Wih, &Whh, &bih, &bhh, &Wcls, &bcls, &out, &hx, &hfin, &ctrs};
  hipError_t e = hipLaunchCooperativeKernel(
      reinterpret_cast<const void*>(&lstm_persist), dim3(NGROUPS * BPG),
      dim3(NTHREADS), args, 0, stream);
  if (e != hipSuccess) {
    lstm_persist<<<dim3(NGROUPS * BPG), dim3(NTHREADS), 0, stream>>>(
        x, Wih, Whh, bih, bhh, Wcls, bcls, out, hx, hfin, ctrs);
  }
}

// Round 3
// 1422.405 us; speedup vs baseline: 4.7217x; 1.5141x over previous
//
#include <hip/hip_runtime.h>
#include <stdint.h>

// LSTM (B=128, T=512, I=64, H=512) persistent kernel, round 3:
//  - 32 groups x 4 batches; 8 blocks/group, 64 units/block, W in VGPRs (2 tiles)
//  - h exchange: tag-embedded u64 granules {u32 tag, 2xbf16}; consumers poll
//    their own granule (flag==data -> one MALL RT, no vmcnt drain, no RMW ctr)
//  - gate math: branchless per-lane nonlinearity + DPP quad broadcasts (no LDS
//    pipe traffic), producer packing shuffle-free
//  - classifier: per-block partials + atomicAdd into zeroed out

#define T_STEPS 512
#define HID 512
#define IND 64
#define NGROUPS 32
#define BPG 8           // blocks per group
#define BATCH_PG 4      // batches per group
#define UPB 64          // hidden units per block
#define NTHREADS 512    // 8 waves; wave w owns gate-cols [w*32, w*32+32) (2 tiles)

typedef float f32x4 __attribute__((ext_vector_type(4)));
typedef short s16x8 __attribute__((ext_vector_type(8)));
typedef unsigned long long u64_t;

#define ALOAD64(p)    __hip_atomic_load((p), __ATOMIC_RELAXED, __HIP_MEMORY_SCOPE_AGENT)
#define ASTORE64(p,v) __hip_atomic_store((p), (v), __ATOMIC_RELAXED, __HIP_MEMORY_SCOPE_AGENT)

__device__ inline unsigned short f2bf(float f) {
  uint32_t u = __builtin_bit_cast(uint32_t, f);
  u += 0x7fffu + ((u >> 16) & 1u);   // RNE (finite inputs)
  return (unsigned short)(u >> 16);
}

__device__ inline s16x8 pack8(f32x4 a, f32x4 b) {
  s16x8 r;
  r[0] = (short)f2bf(a[0]); r[1] = (short)f2bf(a[1]);
  r[2] = (short)f2bf(a[2]); r[3] = (short)f2bf(a[3]);
  r[4] = (short)f2bf(b[0]); r[5] = (short)f2bf(b[1]);
  r[6] = (short)f2bf(b[2]); r[7] = (short)f2bf(b[3]);
  return r;
}

template <int CTRL>
__device__ inline float qbc(float v) {   // quad_perm broadcast via DPP (VALU)
  int i = __builtin_bit_cast(int, v);
  return __builtin_bit_cast(float,
      __builtin_amdgcn_update_dpp(i, i, CTRL, 0xF, 0xF, false));
}

__global__ void __launch_bounds__(NTHREADS, 2)
lstm_persist(const float* __restrict__ x,   const float* __restrict__ Wih,
             const float* __restrict__ Whh, const float* __restrict__ bih,
             const float* __restrict__ bhh, const float* __restrict__ Wcls,
             const float* __restrict__ bcls, float* __restrict__ out,
             u64_t* __restrict__ hx)   // [2][NGROUPS][1024] u64, memset 0
{
  __shared__ unsigned short hsm[16 * HID];        // 16KB A-tile (swizzled)
  __shared__ float clsh[BATCH_PG][UPB];           // 1KB final-h for classifier

  const int g    = blockIdx.x / BPG;
  const int blk  = blockIdx.x % BPG;
  const int tid  = threadIdx.x;
  const int w    = tid >> 6;
  const int lane = tid & 63;
  const int lrow = lane & 15;   // A row / D col
  const int lk   = lane >> 4;   // K subgroup

  // ---- persistent weight fragments: 2 col-tiles x 18 K-chunks ----
  s16x8 wf[2][18];
  float bias[2];
#pragma unroll
  for (int n = 0; n < 2; ++n) {
    const int c    = w * 32 + n * 16 + lrow;       // local gate-col 0..255
    const int grow = (c & 3) * HID + blk * UPB + (c >> 2);
#pragma unroll
    for (int kk = 0; kk < 16; ++kk) {
      const float* p = Whh + (size_t)grow * HID + kk * 32 + lk * 8;
      wf[n][kk] = pack8(*(const f32x4*)p, *(const f32x4*)(p + 4));
    }
#pragma unroll
    for (int kk = 0; kk < 2; ++kk) {
      const float* p = Wih + (size_t)grow * IND + kk * 32 + lk * 8;
      wf[n][16 + kk] = pack8(*(const f32x4*)p, *(const f32x4*)(p + 4));
    }
    bias[n] = bih[grow] + bhh[grow];
  }

  // zero A-tile rows 4..15 (padding rows), once
  {
    u64_t* z = (u64_t*)(hsm + 4 * HID);
    for (int i = tid; i < 1536; i += NTHREADS) z[i] = 0;
  }
  __syncthreads();

  const bool is_gg = ((lrow & 3) == 2);           // tanh gate column
  const bool prod  = (lk == 0) && ((lane & 3) == 0);
  float cst[2][4] = {{0.f, 0.f, 0.f, 0.f}, {0.f, 0.f, 0.f, 0.f}};
  float hn[2][4];

  const int xb = g * BATCH_PG + (lrow & 3);
  const float* xrow = x + (size_t)xb * (T_STEPS * IND) + lk * 8;
  const s16x8 zero8 = {0, 0, 0, 0, 0, 0, 0, 0};

  for (int t = 0; t < T_STEPS; ++t) {
    const int rb = t & 1;

    // x_t fragments (L2-cached, prefetched before poll)
    s16x8 ax0 = zero8, ax1 = zero8;
    if (lrow < BATCH_PG) {
      const float* p = xrow + (size_t)t * IND;
      ax0 = pack8(*(const f32x4*)p,        *(const f32x4*)(p + 4));
      ax1 = pack8(*(const f32x4*)(p + 32), *(const f32x4*)(p + 36));
    }

    // poll own granule pair until tag == t (flag IS data)
    const u64_t* gp = hx + ((size_t)(rb * NGROUPS + g) << 10);
    u64_t v0 = ALOAD64(gp + 2 * tid), v1 = ALOAD64(gp + 2 * tid + 1);
    const unsigned tg = (unsigned)t;
    while ((unsigned)v0 != tg || (unsigned)v1 != tg) {
      __builtin_amdgcn_s_sleep(1);
      if ((unsigned)v0 != tg) v0 = ALOAD64(gp + 2 * tid);
      if ((unsigned)v1 != tg) v1 = ALOAD64(gp + 2 * tid + 1);
    }
    const unsigned hp0 = (unsigned)(v0 >> 32), hp1 = (unsigned)(v1 >> 32);

    // scatter unit tid's 4 batch values into swizzled LDS tile
    {
      char* hb = (char*)hsm;
      const int gcol = tid >> 3, sub = (tid & 7) << 1;
      *(unsigned short*)(hb + 0 * 1024 + (((gcol ^ 0) << 4) | sub)) = (unsigned short)hp0;
      *(unsigned short*)(hb + 1 * 1024 + (((gcol ^ 1) << 4) | sub)) = (unsigned short)(hp0 >> 16);
      *(unsigned short*)(hb + 2 * 1024 + (((gcol ^ 2) << 4) | sub)) = (unsigned short)hp1;
      *(unsigned short*)(hb + 3 * 1024 + (((gcol ^ 3) << 4) | sub)) = (unsigned short)(hp1 >> 16);
    }

    // x MFMAs while the tile settles
    f32x4 acc0 = {0.f, 0.f, 0.f, 0.f}, acc1 = {0.f, 0.f, 0.f, 0.f};
    acc0 = __builtin_amdgcn_mfma_f32_16x16x32_bf16(ax0, wf[0][16], acc0, 0, 0, 0);
    acc0 = __builtin_amdgcn_mfma_f32_16x16x32_bf16(ax1, wf[0][17], acc0, 0, 0, 0);
    acc1 = __builtin_amdgcn_mfma_f32_16x16x32_bf16(ax0, wf[1][16], acc1, 0, 0, 0);
    acc1 = __builtin_amdgcn_mfma_f32_16x16x32_bf16(ax1, wf[1][17], acc1, 0, 0, 0);

    __syncthreads();

    // h MFMAs from swizzled LDS (4 chunks of 4 to cap VGPRs)
    const char* rowp = (const char*)hsm + lrow * 1024;
    const int rxor = lrow & 7;
#pragma unroll
    for (int kk4 = 0; kk4 < 4; ++kk4) {
      s16x8 ah[4];
#pragma unroll
      for (int j = 0; j < 4; ++j)
        ah[j] = *(const s16x8*)(rowp + (((4 * (kk4 * 4 + j) + lk) ^ rxor) << 4));
#pragma unroll
      for (int j = 0; j < 4; ++j) {
        acc0 = __builtin_amdgcn_mfma_f32_16x16x32_bf16(ah[j], wf[0][kk4 * 4 + j], acc0, 0, 0, 0);
        acc1 = __builtin_amdgcn_mfma_f32_16x16x32_bf16(ah[j], wf[1][kk4 * 4 + j], acc1, 0, 0, 0);
      }
    }

    __syncthreads();   // tile fully consumed; next iter may overwrite

    // gates: branchless nonlinearity + DPP quad broadcasts
#pragma unroll
    for (int n = 0; n < 2; ++n) {
      const f32x4 accn = n ? acc1 : acc0;
#pragma unroll
      for (int r = 0; r < 4; ++r) {
        const float v  = accn[r] + bias[n];
        const float a  = is_gg ? (2.f * v) : (-v);
        const float e  = __expf(a);
        const float r1 = __builtin_amdgcn_rcpf(1.f + e);
        const float sg = is_gg ? (1.f - 2.f * r1) : r1;   // tanh or sigmoid
        const float vi = qbc<0x00>(sg);
        const float vf = qbc<0x55>(sg);
        const float vg = qbc<0xAA>(sg);
        const float vo = qbc<0xFF>(sg);
        const float c  = fmaf(vf, cst[n][r], vi * vg);
        cst[n][r] = c;
        const float th = 1.f - 2.f * __builtin_amdgcn_rcpf(1.f + __expf(2.f * c));
        hn[n][r] = vo * th;
      }
    }

    // producer lanes store tagged granules (fire-and-forget)
    u64_t* op = hx + ((size_t)((rb ^ 1) * NGROUPS + g) << 10);
    const u64_t ntg = (u64_t)(unsigned)(t + 1);
    if (prod) {
#pragma unroll
      for (int n = 0; n < 2; ++n) {
        const int ul = w * 8 + n * 4 + (lrow >> 2);     // local unit 0..63
        const int gu = blk * UPB + ul;                  // global unit 0..511
        const unsigned p01 = (unsigned)f2bf(hn[n][0]) | ((unsigned)f2bf(hn[n][1]) << 16);
        const unsigned p23 = (unsigned)f2bf(hn[n][2]) | ((unsigned)f2bf(hn[n][3]) << 16);
        ASTORE64(op + 2 * gu,     ntg | ((u64_t)p01 << 32));
        ASTORE64(op + 2 * gu + 1, ntg | ((u64_t)p23 << 32));
        if (t == T_STEPS - 1) {
#pragma unroll
          for (int r = 0; r < 4; ++r) clsh[r][ul] = hn[n][r];
        }
      }
    }
  }

  // ---- classifier: per-block partials over its 64 units ----
  __syncthreads();
  if (w == 0) {
#pragma unroll
    for (int b = 0; b < BATCH_PG; ++b) {
      const float hv = clsh[b][lane];
      for (int cls = 0; cls < 10; ++cls) {
        float v = hv * Wcls[(size_t)cls * HID + blk * UPB + lane];
#pragma unroll
        for (int m = 32; m >= 1; m >>= 1) v += __shfl_xor(v, m);
        if (lane == 0) {
          if (blk == 0) v += bcls[cls];
          atomicAdd(&out[(g * BATCH_PG + b) * 10 + cls], v);
        }
      }
    }
  }
}

extern "C" void kernel_launch(void* const* d_in, const int* in_sizes, int n_in,
                              void* d_out, int out_size, void* d_ws, size_t ws_size,
                              hipStream_t stream) {
  const float* x    = (const float*)d_in[0];
  const float* Wih  = (const float*)d_in[1];
  const float* Whh  = (const float*)d_in[2];
  const float* bih  = (const float*)d_in[3];
  const float* bhh  = (const float*)d_in[4];
  const float* Wcls = (const float*)d_in[5];
  const float* bcls = (const float*)d_in[6];
  float* out = (float*)d_out;

  u64_t* hx = (u64_t*)d_ws;   // [2][32][1024] u64 = 512 KiB

  // replay-safe re-init: zero tags (tag0 == step-0 data h=0) and output accum
  hipMemsetAsync(hx, 0, 2 * NGROUPS * 1024 * sizeof(u64_t), stream);
  hipMemsetAsync(out, 0, (size_t)out_size * sizeof(float), stream);

  void* args[] = {&x, &Wih, &Whh, &bih, &bhh, &Wcls, &bcls, &out, &hx};
  hipError_t e = hipLaunchCooperativeKernel(
      reinterpret_cast<const void*>(&lstm_persist), dim3(NGROUPS * BPG),
      dim3(NTHREADS), args, 0, stream);
  if (e != hipSuccess) {
    lstm_persist<<<dim3(NGROUPS * BPG), dim3(NTHREADS), 0, stream>>>(
        x, Wih, Whh, bih, bhh, Wcls, bcls, out, hx);
  }
}

// Round 4
// 1416.001 us; speedup vs baseline: 4.7431x; 1.0045x over previous
//
#include <hip/hip_runtime.h>
#include <stdint.h>

// LSTM (B=128, T=512, I=64, H=512) persistent kernel, round 4:
//  - 32 groups x 4 batches; 8 blocks/group, 64 units/block, W in VGPRs (2 tiles)
//  - h exchange: tag-embedded u64 granules {u32 tag, 2xbf16}, relaxed agent atomics
//  - LDS A-tile: 4 real rows only, double-buffered (2x4KB); masked ds_read_b128
//    (16 active lanes) -- padding rows live as persistent zero VGPRs
//  - scatter: DPP quad-swap pairing -> full-dword conflict-free ds_write_b32
//  - one __syncthreads per step

#define T_STEPS 512
#define HID 512
#define IND 64
#define NGROUPS 32
#define BPG 8           // blocks per group
#define BATCH_PG 4      // batches per group
#define UPB 64          // hidden units per block
#define NTHREADS 512    // 8 waves; wave w owns gate-cols [w*32, w*32+32) (2 tiles)

typedef float f32x4 __attribute__((ext_vector_type(4)));
typedef short s16x8 __attribute__((ext_vector_type(8)));
typedef unsigned long long u64_t;

#define ALOAD64(p)    __hip_atomic_load((p), __ATOMIC_RELAXED, __HIP_MEMORY_SCOPE_AGENT)
#define ASTORE64(p,v) __hip_atomic_store((p), (v), __ATOMIC_RELAXED, __HIP_MEMORY_SCOPE_AGENT)

__device__ inline unsigned short f2bf(float f) {
  uint32_t u = __builtin_bit_cast(uint32_t, f);
  u += 0x7fffu + ((u >> 16) & 1u);   // RNE (finite inputs)
  return (unsigned short)(u >> 16);
}

__device__ inline s16x8 pack8(f32x4 a, f32x4 b) {
  s16x8 r;
  r[0] = (short)f2bf(a[0]); r[1] = (short)f2bf(a[1]);
  r[2] = (short)f2bf(a[2]); r[3] = (short)f2bf(a[3]);
  r[4] = (short)f2bf(b[0]); r[5] = (short)f2bf(b[1]);
  r[6] = (short)f2bf(b[2]); r[7] = (short)f2bf(b[3]);
  return r;
}

template <int CTRL>
__device__ inline float qbc(float v) {   // quad_perm broadcast via DPP (VALU)
  int i = __builtin_bit_cast(int, v);
  return __builtin_bit_cast(float,
      __builtin_amdgcn_update_dpp(i, i, CTRL, 0xF, 0xF, false));
}

__device__ inline unsigned qswap(unsigned v) {  // quad_perm [1,0,3,2]
  int i = __builtin_bit_cast(int, v);
  return (unsigned)__builtin_amdgcn_update_dpp(i, i, 0xB1, 0xF, 0xF, false);
}

__global__ void __launch_bounds__(NTHREADS, 2)
lstm_persist(const float* __restrict__ x,   const float* __restrict__ Wih,
             const float* __restrict__ Whh, const float* __restrict__ bih,
             const float* __restrict__ bhh, const float* __restrict__ Wcls,
             const float* __restrict__ bcls, float* __restrict__ out,
             u64_t* __restrict__ hx)   // [2][NGROUPS][1024] u64, memset 0
{
  __shared__ unsigned short hsm[2][4 * HID];      // 2 x 4KB A-tile (rows 0..3)
  __shared__ float clsh[BATCH_PG][UPB];           // 1KB final-h for classifier

  const int g    = blockIdx.x / BPG;
  const int blk  = blockIdx.x % BPG;
  const int tid  = threadIdx.x;
  const int w    = tid >> 6;
  const int lane = tid & 63;
  const int lrow = lane & 15;   // A row / D col
  const int lk   = lane >> 4;   // K subgroup

  // ---- persistent weight fragments: 2 col-tiles x 18 K-chunks ----
  s16x8 wf[2][18];
  float bias[2];
#pragma unroll
  for (int n = 0; n < 2; ++n) {
    const int c    = w * 32 + n * 16 + lrow;       // local gate-col 0..255
    const int grow = (c & 3) * HID + blk * UPB + (c >> 2);
#pragma unroll
    for (int kk = 0; kk < 16; ++kk) {
      const float* p = Whh + (size_t)grow * HID + kk * 32 + lk * 8;
      wf[n][kk] = pack8(*(const f32x4*)p, *(const f32x4*)(p + 4));
    }
#pragma unroll
    for (int kk = 0; kk < 2; ++kk) {
      const float* p = Wih + (size_t)grow * IND + kk * 32 + lk * 8;
      wf[n][16 + kk] = pack8(*(const f32x4*)p, *(const f32x4*)(p + 4));
    }
    bias[n] = bih[grow] + bhh[grow];
  }

  const bool is_gg = ((lrow & 3) == 2);           // tanh gate column
  const bool arow  = (lrow < BATCH_PG);           // lanes holding real A rows
  const bool prod  = (lk == 0) && ((lane & 3) == 0);
  float cst[2][4] = {{0.f, 0.f, 0.f, 0.f}, {0.f, 0.f, 0.f, 0.f}};
  float hn[2][4];

  // persistent A fragments: inactive lanes stay zero forever (masked loads)
  s16x8 ah[4] = {};
  s16x8 ax0 = {}, ax1 = {};

  const int xb = g * BATCH_PG + (lrow & 3);
  const float* xrow = x + (size_t)xb * (T_STEPS * IND) + lk * 8;

  // precomputed scatter constants (DPP-paired dword writes)
  const bool evn = (tid & 1) == 0;
  const int  ue  = tid & ~1;
  const int  sc_base = ((ue >> 3) << 4) + (ue & 7) * 2;   // slot*16 + byte
  const int  addr01 = (evn ? 0 : 1024) + (sc_base ^ (evn ? 0 : (4 << 4)));
  const int  addr23 = (evn ? 2048 : 3072) + (sc_base ^ (evn ? (8 << 4) : (12 << 4)));

  for (int t = 0; t < T_STEPS; ++t) {
    const int rb = t & 1;

    // x_t fragments (masked global loads; overlap the poll)
    if (arow) {
      const float* p = xrow + (size_t)t * IND;
      ax0 = pack8(*(const f32x4*)p,        *(const f32x4*)(p + 4));
      ax1 = pack8(*(const f32x4*)(p + 32), *(const f32x4*)(p + 36));
    }

    // poll own granule pair until tag == t (flag IS data)
    const u64_t* gp = hx + ((size_t)(rb * NGROUPS + g) << 10);
    u64_t v0 = ALOAD64(gp + 2 * tid), v1 = ALOAD64(gp + 2 * tid + 1);
    const unsigned tg = (unsigned)t;
    while ((unsigned)v0 != tg || (unsigned)v1 != tg) {
      __builtin_amdgcn_s_sleep(1);
      if ((unsigned)v0 != tg) v0 = ALOAD64(gp + 2 * tid);
      if ((unsigned)v1 != tg) v1 = ALOAD64(gp + 2 * tid + 1);
    }
    const unsigned hp0 = (unsigned)(v0 >> 32), hp1 = (unsigned)(v1 >> 32);

    // scatter: pair halves with quad neighbor -> 2 full-dword LDS writes
    {
      char* hb = (char*)hsm[rb];
      const unsigned q0 = qswap(hp0), q1 = qswap(hp1);
      const unsigned v01 = evn ? ((hp0 & 0xffffu) | (q0 << 16))
                               : ((q0 >> 16) | (hp0 & 0xffff0000u));
      const unsigned v23 = evn ? ((hp1 & 0xffffu) | (q1 << 16))
                               : ((q1 >> 16) | (hp1 & 0xffff0000u));
      *(unsigned*)(hb + addr01) = v01;
      *(unsigned*)(hb + addr23) = v23;
    }

    // x MFMAs while the tile settles
    f32x4 acc0 = {0.f, 0.f, 0.f, 0.f}, acc1 = {0.f, 0.f, 0.f, 0.f};
    acc0 = __builtin_amdgcn_mfma_f32_16x16x32_bf16(ax0, wf[0][16], acc0, 0, 0, 0);
    acc0 = __builtin_amdgcn_mfma_f32_16x16x32_bf16(ax1, wf[0][17], acc0, 0, 0, 0);
    acc1 = __builtin_amdgcn_mfma_f32_16x16x32_bf16(ax0, wf[1][16], acc1, 0, 0, 0);
    acc1 = __builtin_amdgcn_mfma_f32_16x16x32_bf16(ax1, wf[1][17], acc1, 0, 0, 0);

    __syncthreads();

    // h MFMAs: masked reads (16 active lanes), rows 0..3 only
    const char* rowp = (const char*)hsm[rb] + lrow * 1024;
    const int rxor = lrow << 2;   // slot ^= (row*4); slot granule = 16B
#pragma unroll
    for (int kk4 = 0; kk4 < 4; ++kk4) {
      if (arow) {
#pragma unroll
        for (int j = 0; j < 4; ++j)
          ah[j] = *(const s16x8*)(rowp + (((16 * kk4 + 4 * j + lk) ^ rxor) << 4));
      }
#pragma unroll
      for (int j = 0; j < 4; ++j) {
        acc0 = __builtin_amdgcn_mfma_f32_16x16x32_bf16(ah[j], wf[0][kk4 * 4 + j], acc0, 0, 0, 0);
        acc1 = __builtin_amdgcn_mfma_f32_16x16x32_bf16(ah[j], wf[1][kk4 * 4 + j], acc1, 0, 0, 0);
      }
    }

    // gates: branchless nonlinearity + DPP quad broadcasts
#pragma unroll
    for (int n = 0; n < 2; ++n) {
      const f32x4 accn = n ? acc1 : acc0;
#pragma unroll
      for (int r = 0; r < 4; ++r) {
        const float v  = accn[r] + bias[n];
        const float a  = is_gg ? (2.f * v) : (-v);
        const float e  = __expf(a);
        const float r1 = __builtin_amdgcn_rcpf(1.f + e);
        const float sg = is_gg ? (1.f - 2.f * r1) : r1;   // tanh or sigmoid
        const float vi = qbc<0x00>(sg);
        const float vf = qbc<0x55>(sg);
        const float vg = qbc<0xAA>(sg);
        const float vo = qbc<0xFF>(sg);
        const float c  = fmaf(vf, cst[n][r], vi * vg);
        cst[n][r] = c;
        const float th = 1.f - 2.f * __builtin_amdgcn_rcpf(1.f + __expf(2.f * c));
        hn[n][r] = vo * th;
      }
    }

    // producer lanes store tagged granules (fire-and-forget)
    u64_t* op = hx + ((size_t)((rb ^ 1) * NGROUPS + g) << 10);
    const u64_t ntg = (u64_t)(unsigned)(t + 1);
    if (prod) {
#pragma unroll
      for (int n = 0; n < 2; ++n) {
        const int ul = w * 8 + n * 4 + (lrow >> 2);     // local unit 0..63
        const int gu = blk * UPB + ul;                  // global unit 0..511
        const unsigned p01 = (unsigned)f2bf(hn[n][0]) | ((unsigned)f2bf(hn[n][1]) << 16);
        const unsigned p23 = (unsigned)f2bf(hn[n][2]) | ((unsigned)f2bf(hn[n][3]) << 16);
        ASTORE64(op + 2 * gu,     ntg | ((u64_t)p01 << 32));
        ASTORE64(op + 2 * gu + 1, ntg | ((u64_t)p23 << 32));
        if (t == T_STEPS - 1) {
#pragma unroll
          for (int r = 0; r < 4; ++r) clsh[r][ul] = hn[n][r];
        }
      }
    }
  }

  // ---- classifier: per-block partials over its 64 units ----
  __syncthreads();
  if (w == 0) {
#pragma unroll
    for (int b = 0; b < BATCH_PG; ++b) {
      const float hv = clsh[b][lane];
      for (int cls = 0; cls < 10; ++cls) {
        float v = hv * Wcls[(size_t)cls * HID + blk * UPB + lane];
#pragma unroll
        for (int m = 32; m >= 1; m >>= 1) v += __shfl_xor(v, m);
        if (lane == 0) {
          if (blk == 0) v += bcls[cls];
          atomicAdd(&out[(g * BATCH_PG + b) * 10 + cls], v);
        }
      }
    }
  }
}

extern "C" void kernel_launch(void* const* d_in, const int* in_sizes, int n_in,
                              void* d_out, int out_size, void* d_ws, size_t ws_size,
                              hipStream_t stream) {
  const float* x    = (const float*)d_in[0];
  const float* Wih  = (const float*)d_in[1];
  const float* Whh  = (const float*)d_in[2];
  const float* bih  = (const float*)d_in[3];
  const float* bhh  = (const float*)d_in[4];
  const float* Wcls = (const float*)d_in[5];
  const float* bcls = (const float*)d_in[6];
  float* out = (float*)d_out;

  u64_t* hx = (u64_t*)d_ws;   // [2][32][1024] u64 = 512 KiB

  // replay-safe re-init: zero tags (tag0 == step-0 data h=0) and output accum
  hipMemsetAsync(hx, 0, 2 * NGROUPS * 1024 * sizeof(u64_t), stream);
  hipMemsetAsync(out, 0, (size_t)out_size * sizeof(float), stream);

  void* args[] = {&x, &Wih, &Whh, &bih, &bhh, &Wcls, &bcls, &out, &hx};
  hipError_t e = hipLaunchCooperativeKernel(
      reinterpret_cast<const void*>(&lstm_persist), dim3(NGROUPS * BPG),
      dim3(NTHREADS), args, 0, stream);
  if (e != hipSuccess) {
    lstm_persist<<<dim3(NGROUPS * BPG), dim3(NTHREADS), 0, stream>>>(
        x, Wih, Whh, bih, bhh, Wcls, bcls, out, hx);
  }
}